// Round 1
// baseline (252.155 us; speedup 1.0000x reference)
//
#include <hip/hip_runtime.h>

#define BLK 256
#define LBLK 256   // layer kernel: 16 threads per node-slot, 2 nodes per slot
#define NPB 32     // nodes per block in k_layer
#define CH 1024    // scan chunk per block (N=200000 -> 196 blocks, <= 256)

// ---------------- bf16 helpers ----------------
__device__ __forceinline__ unsigned short f2bf(float f) {
    unsigned u = __float_as_uint(f);
    u += 0x7FFFu + ((u >> 16) & 1u);       // round-to-nearest-even
    return (unsigned short)(u >> 16);
}
__device__ __forceinline__ float bf2f(unsigned short h) {
    return __uint_as_float((unsigned)h << 16);
}
__device__ __forceinline__ float4 unpack4(ushort4 h) {
    return make_float4(bf2f(h.x), bf2f(h.y), bf2f(h.z), bf2f(h.w));
}
__device__ __forceinline__ ushort4 pack4(float4 f) {
    ushort4 h; h.x = f2bf(f.x); h.y = f2bf(f.y); h.z = f2bf(f.z); h.w = f2bf(f.w);
    return h;
}

// ---------------- setup kernels ----------------

// count degree by dst AND record each edge's rank within its dst row
__global__ void k_deg(const int* __restrict__ dst, int* __restrict__ deg,
                      int* __restrict__ rank, int E) {
    int e = blockIdx.x * blockDim.x + threadIdx.x;
    if (e < E) rank[e] = atomicAdd(&deg[dst[e]], 1);
}

// per-chunk sums (int4 loads, one reduce per block)
__global__ void k_scan1(const int* __restrict__ deg, int* __restrict__ partials, int N) {
    __shared__ int sm[BLK];
    int i0 = blockIdx.x * CH + threadIdx.x * 4;
    int s = 0;
    if (i0 + 3 < N) {
        int4 v = *(const int4*)(deg + i0);
        s = (v.x + v.y) + (v.z + v.w);
    } else {
        for (int k = 0; k < 4; ++k) if (i0 + k < N) s += deg[i0 + k];
    }
    sm[threadIdx.x] = s;
    __syncthreads();
    for (int off = BLK / 2; off > 0; off >>= 1) {
        if (threadIdx.x < off) sm[threadIdx.x] += sm[threadIdx.x + off];
        __syncthreads();
    }
    if (threadIdx.x == 0) partials[blockIdx.x] = sm[0];
}

// fused: redundant scan of partials for block base, then one vectorized
// LDS-scan tile over this block's 1024-element chunk -> row_off
__global__ void k_scan2(const int* __restrict__ deg, const int* __restrict__ partials,
                        int* __restrict__ row_off, int N, int E, int nb) {
    __shared__ int sp[BLK];
    __shared__ int sm[BLK];
    int b = blockIdx.x, t = threadIdx.x;
    sp[t] = (t < nb) ? partials[t] : 0;
    __syncthreads();
    for (int off = 1; off < BLK; off <<= 1) {
        int add = (t >= off) ? sp[t - off] : 0;
        __syncthreads();
        sp[t] += add;
        __syncthreads();
    }
    int base = (b == 0) ? 0 : sp[b - 1];
    if (b == 0 && t == 0) row_off[N] = E;
    int i0 = b * CH + t * 4;
    int v0 = 0, v1 = 0, v2 = 0, v3 = 0;
    if (i0 + 3 < N) {
        int4 v = *(const int4*)(deg + i0);
        v0 = v.x; v1 = v.y; v2 = v.z; v3 = v.w;
    } else {
        if (i0     < N) v0 = deg[i0];
        if (i0 + 1 < N) v1 = deg[i0 + 1];
        if (i0 + 2 < N) v2 = deg[i0 + 2];
    }
    int tot = (v0 + v1) + (v2 + v3);
    sm[t] = tot;
    __syncthreads();
    for (int off = 1; off < BLK; off <<= 1) {
        int add = (t >= off) ? sm[t - off] : 0;
        __syncthreads();
        sm[t] += add;
        __syncthreads();
    }
    int excl = base + sm[t] - tot;
    int4 r;
    r.x = excl;
    r.y = excl + v0;
    r.z = excl + v0 + v1;
    r.w = excl + v0 + v1 + v2;
    if (i0 + 3 < N) {
        *(int4*)(row_off + i0) = r;
    } else {
        if (i0     < N) row_off[i0]     = r.x;
        if (i0 + 1 < N) row_off[i0 + 1] = r.y;
        if (i0 + 2 < N) row_off[i0 + 2] = r.z;
    }
}

// fused conv + fill (independent jobs, one dispatch):
//  blocks [0,gF): atomic-free CSR fill, 8B records {src, bf16 a | bf16 r << 16}
//  blocks [gF,..): embs[v] = bf16(dinv[v] * emb[v])
__global__ void k_convfill(const int* __restrict__ src, const int* __restrict__ dst,
                           const float2* __restrict__ attrs, const int* __restrict__ row_off,
                           const int* __restrict__ rank, const int* __restrict__ deg,
                           uint2* __restrict__ csr, const float4* __restrict__ emb4,
                           ushort4* __restrict__ embs, int E, int N16, int gF) {
    int b = blockIdx.x;
    if (b < gF) {
        int e = b * BLK + threadIdx.x;
        if (e >= E) return;
        int pos = row_off[dst[e]] + rank[e];
        float2 ar = attrs[e];
        csr[pos] = make_uint2((unsigned)src[e],
                              (unsigned)f2bf(ar.x) | ((unsigned)f2bf(ar.y) << 16));
    } else {
        int i = (b - gF) * BLK + threadIdx.x;
        if (i >= N16) return;
        int d = deg[i >> 4];
        float dinv = (d > 0) ? rsqrtf((float)d) : 0.0f;
        float4 e = emb4[i];
        embs[i] = pack4(make_float4(dinv * e.x, dinv * e.y, dinv * e.z, dinv * e.w));
    }
}

// ---------------- per-layer kernel ----------------
// 16 threads per node, 4 dims each (bf16x4), TWO nodes per 16-thread group.
// Doubles memory-level parallelism: both nodes' csr loads issue, then both
// nodes' gathers, so the second dependent chain overlaps the first
// (latency-bound gather path — HBM is at 37%, VALU real issue ~35%).
// xs rows PRE-SCALED by dinv[src].
// x_new[v] = dinv[v] * (Σ w·xs[src]) / (Σ w + eps)
// Peeled first round covers deg<=4 (89% of nodes) branch-free via clamped
// indices + mask weights; rare deg>4 tail uses the old 4-edge loop.

__device__ __forceinline__ float lrelu(float x) { return fmaxf(x, 0.01f * x); }

__device__ __forceinline__ float4 edge_w4(unsigned ar, const float4& aw, const float4& rw) {
    float a = bf2f((unsigned short)(ar & 0xffffu));
    float r = bf2f((unsigned short)(ar >> 16));
    float4 w;
    w.x = __expf(lrelu(a * aw.x) + lrelu(r * rw.x));
    w.y = __expf(lrelu(a * aw.y) + lrelu(r * rw.y));
    w.z = __expf(lrelu(a * aw.z) + lrelu(r * rw.z));
    w.w = __expf(lrelu(a * aw.w) + lrelu(r * rw.w));
    return w;
}

__device__ __forceinline__ void acc4(float4& num, float4& den,
                                     const float4& w, const ushort4& h, float g) {
    float4 x = unpack4(h);
    den.x += g * w.x; den.y += g * w.y; den.z += g * w.z; den.w += g * w.w;
    num.x += g * w.x * x.x;
    num.y += g * w.y * x.y;
    num.z += g * w.z * x.z;
    num.w += g * w.w * x.w;
}

template<int MODE>
__device__ __forceinline__ void store_node(
    int v, int d4, int dv, const float4& num, const float4& den,
    const float4* __restrict__ emb4, const ushort4* __restrict__ xsA,
    const ushort4* __restrict__ xsB, ushort4* __restrict__ xsout,
    float4* __restrict__ out4) {
    float4 xr;   // raw ratio, before dinv[v] scaling
    xr.x = num.x / (den.x + 1e-16f);
    xr.y = num.y / (den.y + 1e-16f);
    xr.z = num.z / (den.z + 1e-16f);
    xr.w = num.w / (den.w + 1e-16f);
    const float dinv = (dv > 0) ? rsqrtf((float)dv) : 0.0f;
    const size_t o = (size_t)v * 16 + d4;
    if (MODE == 2) {
        const float sd = (dv > 0) ? sqrtf((float)dv) : 0.0f;
        float4 e = emb4[o];
        float4 A = unpack4(xsA[o]);
        float4 B = unpack4(xsB[o]);
        float4 r;
        r.x = (e.x + sd * (A.x + B.x) + dinv * xr.x) * 0.25f;
        r.y = (e.y + sd * (A.y + B.y) + dinv * xr.y) * 0.25f;
        r.z = (e.z + sd * (A.z + B.z) + dinv * xr.z) * 0.25f;
        r.w = (e.w + sd * (A.w + B.w) + dinv * xr.w) * 0.25f;
        out4[o] = r;
    } else {
        const float s = dinv * dinv;   // store dinv[v] * x_new = dinv^2 * xr
        xsout[o] = pack4(make_float4(s * xr.x, s * xr.y, s * xr.z, s * xr.w));
    }
}

template<int MODE>
__global__ __launch_bounds__(LBLK) void k_layer(
    const ushort4* __restrict__ xs, const uint2* __restrict__ csr,
    const int* __restrict__ row_off,
    const float4* __restrict__ aw4, const float4* __restrict__ rw4,
    const float4* __restrict__ emb4,
    const ushort4* __restrict__ xsA, const ushort4* __restrict__ xsB,
    ushort4* __restrict__ xsout, float4* __restrict__ out4, int N) {
    const int t = threadIdx.x;
    const int d4 = t & 15;
    const int vA = blockIdx.x * NPB + (t >> 4);
    const int vB = vA + 16;
    const unsigned nm1 = (unsigned)(N - 1);

    const float4 aw = aw4[d4];
    const float4 rw = rw4[d4];

    // row offsets for both nodes (clamped: N % NPB == 0 in practice)
    const int a_ = min(vA, N - 1);
    const int b_ = min(vB, N - 1);
    const int s0A = row_off[a_], s1A = row_off[a_ + 1];
    const int s0B = row_off[b_], s1B = row_off[b_ + 1];
    const int lA = max(s1A - 1, s0A);   // deg-0 safe clamp target
    const int lB = max(s1B - 1, s0B);

    // --- issue BOTH csr rounds (8 loads in flight) ---
    uint2 eA0 = csr[s0A];
    uint2 eA1 = csr[min(s0A + 1, lA)];
    uint2 eA2 = csr[min(s0A + 2, lA)];
    uint2 eA3 = csr[min(s0A + 3, lA)];
    uint2 eB0 = csr[s0B];
    uint2 eB1 = csr[min(s0B + 1, lB)];
    uint2 eB2 = csr[min(s0B + 2, lB)];
    uint2 eB3 = csr[min(s0B + 3, lB)];

    // --- issue BOTH gather rounds (8 × 128B rows in flight per node pair) ---
    // src index clamped so garbage from deg-0 padding can't fault.
    ushort4 hA0 = xs[(size_t)min(eA0.x, nm1) * 16 + d4];
    ushort4 hA1 = xs[(size_t)min(eA1.x, nm1) * 16 + d4];
    ushort4 hA2 = xs[(size_t)min(eA2.x, nm1) * 16 + d4];
    ushort4 hA3 = xs[(size_t)min(eA3.x, nm1) * 16 + d4];
    ushort4 hB0 = xs[(size_t)min(eB0.x, nm1) * 16 + d4];
    ushort4 hB1 = xs[(size_t)min(eB1.x, nm1) * 16 + d4];
    ushort4 hB2 = xs[(size_t)min(eB2.x, nm1) * 16 + d4];
    ushort4 hB3 = xs[(size_t)min(eB3.x, nm1) * 16 + d4];

    float4 numA = {0.f, 0.f, 0.f, 0.f}, denA = {0.f, 0.f, 0.f, 0.f};
    float4 numB = {0.f, 0.f, 0.f, 0.f}, denB = {0.f, 0.f, 0.f, 0.f};

    {   // node A, peeled round (mask-weighted, branch-free)
        const float g0 = (s0A     < s1A) ? 1.0f : 0.0f;
        const float g1 = (s0A + 1 < s1A) ? 1.0f : 0.0f;
        const float g2 = (s0A + 2 < s1A) ? 1.0f : 0.0f;
        const float g3 = (s0A + 3 < s1A) ? 1.0f : 0.0f;
        float4 w0 = edge_w4(eA0.y, aw, rw);
        float4 w1 = edge_w4(eA1.y, aw, rw);
        float4 w2 = edge_w4(eA2.y, aw, rw);
        float4 w3 = edge_w4(eA3.y, aw, rw);
        acc4(numA, denA, w0, hA0, g0);
        acc4(numA, denA, w1, hA1, g1);
        acc4(numA, denA, w2, hA2, g2);
        acc4(numA, denA, w3, hA3, g3);
    }
    {   // node B, peeled round
        const float g0 = (s0B     < s1B) ? 1.0f : 0.0f;
        const float g1 = (s0B + 1 < s1B) ? 1.0f : 0.0f;
        const float g2 = (s0B + 2 < s1B) ? 1.0f : 0.0f;
        const float g3 = (s0B + 3 < s1B) ? 1.0f : 0.0f;
        float4 w0 = edge_w4(eB0.y, aw, rw);
        float4 w1 = edge_w4(eB1.y, aw, rw);
        float4 w2 = edge_w4(eB2.y, aw, rw);
        float4 w3 = edge_w4(eB3.y, aw, rw);
        acc4(numB, denB, w0, hB0, g0);
        acc4(numB, denB, w1, hB1, g1);
        acc4(numB, denB, w2, hB2, g2);
        acc4(numB, denB, w3, hB3, g3);
    }

    // --- rare tails (deg > 4, ~11% of nodes) ---
    for (int i = s0A + 4; i < s1A; i += 4) {
        const int last = s1A - 1;
        uint2 e0 = csr[i];
        uint2 e1 = csr[min(i + 1, last)];
        uint2 e2 = csr[min(i + 2, last)];
        uint2 e3 = csr[min(i + 3, last)];
        ushort4 h0 = xs[(size_t)e0.x * 16 + d4];
        ushort4 h1 = xs[(size_t)e1.x * 16 + d4];
        ushort4 h2 = xs[(size_t)e2.x * 16 + d4];
        ushort4 h3 = xs[(size_t)e3.x * 16 + d4];
        float4 w0 = edge_w4(e0.y, aw, rw);
        float4 w1 = edge_w4(e1.y, aw, rw);
        float4 w2 = edge_w4(e2.y, aw, rw);
        float4 w3 = edge_w4(e3.y, aw, rw);
        float g1 = (i + 1 < s1A) ? 1.0f : 0.0f;
        float g2 = (i + 2 < s1A) ? 1.0f : 0.0f;
        float g3 = (i + 3 < s1A) ? 1.0f : 0.0f;
        acc4(numA, denA, w0, h0, 1.0f);
        acc4(numA, denA, w1, h1, g1);
        acc4(numA, denA, w2, h2, g2);
        acc4(numA, denA, w3, h3, g3);
    }
    for (int i = s0B + 4; i < s1B; i += 4) {
        const int last = s1B - 1;
        uint2 e0 = csr[i];
        uint2 e1 = csr[min(i + 1, last)];
        uint2 e2 = csr[min(i + 2, last)];
        uint2 e3 = csr[min(i + 3, last)];
        ushort4 h0 = xs[(size_t)e0.x * 16 + d4];
        ushort4 h1 = xs[(size_t)e1.x * 16 + d4];
        ushort4 h2 = xs[(size_t)e2.x * 16 + d4];
        ushort4 h3 = xs[(size_t)e3.x * 16 + d4];
        float4 w0 = edge_w4(e0.y, aw, rw);
        float4 w1 = edge_w4(e1.y, aw, rw);
        float4 w2 = edge_w4(e2.y, aw, rw);
        float4 w3 = edge_w4(e3.y, aw, rw);
        float g1 = (i + 1 < s1B) ? 1.0f : 0.0f;
        float g2 = (i + 2 < s1B) ? 1.0f : 0.0f;
        float g3 = (i + 3 < s1B) ? 1.0f : 0.0f;
        acc4(numB, denB, w0, h0, 1.0f);
        acc4(numB, denB, w1, h1, g1);
        acc4(numB, denB, w2, h2, g2);
        acc4(numB, denB, w3, h3, g3);
    }

    if (vA < N) store_node<MODE>(vA, d4, s1A - s0A, numA, denA, emb4, xsA, xsB, xsout, out4);
    if (vB < N) store_node<MODE>(vB, d4, s1B - s0B, numB, denB, emb4, xsA, xsB, xsout, out4);
}

// ---------------- launch ----------------

extern "C" void kernel_launch(void* const* d_in, const int* in_sizes, int n_in,
                              void* d_out, int out_size, void* d_ws, size_t ws_size,
                              hipStream_t stream) {
    const int*   ei    = (const int*)d_in[0];
    const float* attrs = (const float*)d_in[1];
    const float* emb   = (const float*)d_in[2];
    const float* a_att = (const float*)d_in[3];
    const float* r_att = (const float*)d_in[4];

    const int E = in_sizes[0] / 2;
    const int N = in_sizes[2] / 64;
    const int* src = ei;
    const int* dst = ei + E;

    char* ws = (char*)d_ws;
    size_t off = 0;
    auto alloc = [&](size_t bytes) {
        void* p = ws + off;
        off += (bytes + 255) & ~(size_t)255;
        return p;
    };
    int*     deg      = (int*)alloc((size_t)N * 4);
    int*     rank     = (int*)alloc((size_t)E * 4);
    int*     row_off  = (int*)alloc((size_t)(N + 1) * 4);
    int*     partials = (int*)alloc((size_t)BLK * 4);
    uint2*   csr      = (uint2*)alloc((size_t)E * 8);
    ushort4* embs     = (ushort4*)alloc((size_t)N * 16 * 8);
    ushort4* xsA      = (ushort4*)alloc((size_t)N * 16 * 8);
    ushort4* xsB      = (ushort4*)alloc((size_t)N * 16 * 8);
    float4*  out      = (float4*)d_out;

    hipMemsetAsync(deg, 0, (size_t)N * 4, stream);

    int gE = (E + BLK - 1) / BLK;
    int nb = (N + CH - 1) / CH;                 // 196 for N=200000 (must be <= 256)
    int gF = gE;
    int gC = (N * 16 + BLK - 1) / BLK;

    k_deg     <<<gE, BLK, 0, stream>>>(dst, deg, rank, E);
    k_scan1   <<<nb, BLK, 0, stream>>>(deg, partials, N);
    k_scan2   <<<nb, BLK, 0, stream>>>(deg, partials, row_off, N, E, nb);
    k_convfill<<<gF + gC, BLK, 0, stream>>>(src, dst, (const float2*)attrs, row_off,
                                            rank, deg, csr, (const float4*)emb,
                                            embs, E, N * 16, gF);

    const float4* emb4 = (const float4*)emb;
    const float4* aw4  = (const float4*)a_att;
    const float4* rw4  = (const float4*)r_att;

    int gL = (N + NPB - 1) / NPB;
    k_layer<0><<<gL, LBLK, 0, stream>>>(embs, csr, row_off, aw4,      rw4,
                                        nullptr, nullptr, nullptr, xsA, nullptr, N);
    k_layer<1><<<gL, LBLK, 0, stream>>>(xsA,  csr, row_off, aw4 + 16, rw4 + 16,
                                        nullptr, nullptr, nullptr, xsB, nullptr, N);
    k_layer<2><<<gL, LBLK, 0, stream>>>(xsB,  csr, row_off, aw4 + 32, rw4 + 32,
                                        emb4, xsA, xsB, nullptr, out, N);
}